// Round 13
// baseline (68.207 us; speedup 1.0000x reference)
//
#include <hip/hip_runtime.h>

// QuantizedConv1d on MI355X (gfx950) — round 13: 8-wave conv, 32-reg acc,
// 24 waves/CU, full-co blocks (xqs staged once).
// B=32, CIN=128, L=4096, COUT=256, K=5, replication pad 2.
//   prep_kernel: x f32 -> xqs i8 [B][4104][128] pre-swizzled (chunk^(row&7)),
//                replication pad materialized; W -> fragment-linear wtf; tbl.
//   conv_fused:  block = 256co x 64l, 512 thr, 8 waves = 4co x 2l,
//                wave = 64co x 32l (acc[4][2] = 32 VGPR). Stage = linear
//                9,216B copy via 9 global_load_lds. i8 MFMA swapped operands.
// Round-12 post-mortem: split helped conv but prep serialized 14us; conv
// still latency-bound at 16 waves/CU (128-reg cap from 64-reg acc).
// Fix: halve acc -> launch_bounds(512,6) -> 85-reg cap, 3 blocks/CU.

#define B_    32
#define CIN   128
#define LEN   4096
#define COUT  256
#define KW    5
#define RPAD  4104   // padded rows per batch: row = gl+4, gl in [-4, 4100)
#define TROWS 72     // staged rows per 64-l tile: gl in [l0-4, l0+67]

#define XQS_BYTES ((size_t)B_ * RPAD * CIN)   // 16,809,984
#define WTF_BYTES (KW * 2 * 16 * 64 * 16)     // 163,840

typedef int          i32x4 __attribute__((ext_vector_type(4)));
typedef float        f32x4 __attribute__((ext_vector_type(4)));
typedef signed char  s8;
typedef unsigned int u32;

// round-half-even(x*20) - 3, clip to [-128,127], as int8.
// (x*20f vs x/0.05f: <=1ulp flips ~1e-6/elem, each moves an output <=0.64 —
// inside the 2.56 absmax threshold; validated passing rounds 6/8-12.)
__device__ __forceinline__ s8 quant_i8(float xv) {
    float q = rintf(xv * 20.0f) - 3.0f;
    q = fminf(fmaxf(q, -128.0f), 127.0f);
    return (s8)(int)q;
}

// Grid 584 = 544 xq-blocks + 40 w-blocks, 256 threads.
__global__ __launch_bounds__(256) void prep_kernel(
        const float* __restrict__ x, const int* __restrict__ w,
        const int* __restrict__ bias, const float* __restrict__ wscale,
        s8* __restrict__ xqs, s8* __restrict__ wtf, float* __restrict__ tbl)
{
    int bx = blockIdx.x, tid = threadIdx.x;
    if (bx < 544) {
        // ---- X: quantize + transpose into pre-swizzled xqs ----
        // Thread = (rowquad rq, chunk c): rows 4rq..4rq+3, ci c*16..c*16+15.
        // Lanes consecutive in rq -> f32x4 loads are 1KB contiguous per j.
        int b = bx / 17, rg = bx % 17;
        int lane = tid & 63, wv = tid >> 6;
        int rq = rg * 64 + lane;              // 0..1087 (1026 valid)
        if (rq >= 1026) return;
        int r0 = rq << 2;
        const float* xbb = x + (size_t)b * CIN * LEN;
        bool interior = (rq >= 1) && (rq <= 1024);
        #pragma unroll
        for (int it = 0; it < 2; ++it) {
            int c = wv + (it << 2);           // chunk 0..7
            union { s8 cc[16]; i32x4 v; } q[4];
            if (interior) {
                const float* src = xbb + (size_t)(c << 4) * LEN + (r0 - 4);
                #pragma unroll
                for (int j = 0; j < 16; ++j) {
                    f32x4 f = *(const f32x4*)(src + (size_t)j * LEN);
                    #pragma unroll
                    for (int m = 0; m < 4; ++m) q[m].cc[j] = quant_i8(f[m]);
                }
            } else {
                #pragma unroll
                for (int j = 0; j < 16; ++j)
                    #pragma unroll
                    for (int m = 0; m < 4; ++m) {
                        int gl = r0 + m - 4;
                        gl = min(max(gl, 0), LEN - 1);
                        q[m].cc[j] = quant_i8(xbb[(size_t)((c << 4) + j) * LEN + gl]);
                    }
            }
            #pragma unroll
            for (int m = 0; m < 4; ++m) {
                int r = r0 + m;
                *(i32x4*)(xqs + ((size_t)b * RPAD + r) * CIN + ((c ^ (r & 7)) << 4)) = q[m].v;
            }
        }
    } else {
        // ---- W -> fragment-linear i8: frag = k*32 + s*16 + co16; lane holds
        // W[co16*16 + (lane&15)][ci = s*64 + (lane>>4)*16 + j], j=0..15.
        int o    = (bx - 544) * 256 + tid;    // 0..10239
        int lane = o & 63, frag = o >> 6;     // frag 0..159
        int k    = frag >> 5;
        int s    = (frag >> 4) & 1;
        int co   = ((frag & 15) << 4) + (lane & 15);
        int ci   = (s << 6) + ((lane >> 4) << 4);
        union { s8 c[16]; i32x4 v; } q;
        #pragma unroll
        for (int j = 0; j < 16; ++j)
            q.c[j] = (s8)w[co * (CIN * KW) + (ci + j) * KW + k];   // |v|<=127
        *(i32x4*)(wtf + (size_t)frag * 1024 + lane * 16) = q.v;

        if (bx == 544) {                      // requant table: sc, off
            int c = tid;                      // 0..255
            float sc = __fdiv_rn(__fmul_rn(0.05f, wscale[c]), 0.1f);
            tbl[c]       = sc;
            tbl[256 + c] = fmaf((float)bias[c], sc, -128.0f);
        }
    }
}

// Block: 256 co x 64 l, 512 threads, 8 waves = 4 co-waves x 2 l-waves.
// Wave = 64co x 32l, acc[4][2] (32 VGPR). LDS: [72 rows][128 ci] i8 = 9,216B,
// linear copy of pre-swizzled xqs (l0 % 64 == 0 -> row&7 identical).
// launch_bounds(512,6): 85-reg cap -> 3 blocks/CU = 24 waves.
// Grid 2048 = B(32) x ltile(64), XCD-chunked remap.
__global__ __launch_bounds__(512, 6) void conv_fused(
        const s8* __restrict__ xqs, const s8* __restrict__ wtf,
        const float* __restrict__ tbl, int* __restrict__ out)
{
    __shared__ __align__(16) s8 smem[TROWS * CIN];   // 9,216 B

    // XCD-contiguous bijective remap (2048 = 8 XCDs x 256): consecutive orig
    // ids = consecutive ltiles of one batch -> same XCD (xqs L2 locality).
    int orig  = (blockIdx.x & 7) * 256 + (blockIdx.x >> 3);
    int ltile = orig & 63;
    int b     = orig >> 6;
    int l0    = ltile << 6;
    int tid   = threadIdx.x;
    int wid   = tid >> 6, lane = tid & 63;
    int lr    = lane & 15, lh = lane >> 4;
    int cog   = (wid & 3) << 6;          // wave co base: 4 x 64
    int wl    = (wid >> 2) << 5;         // wave local-l base {0, 32}

    // ---- stage: linear 9,216B tile copy, 9 global_load_lds (width 16).
    // LDS dst = wave-uniform base + lane*16 (HW); global src per-lane linear.
    const s8* src = xqs + ((size_t)b * RPAD + l0) * CIN;
    for (int i = wid; i < 9; i += 8)
        __builtin_amdgcn_global_load_lds(
            (const __attribute__((address_space(1))) u32*)(src + (i << 10) + (lane << 4)),
            (__attribute__((address_space(3))) u32*)(smem + (i << 10)),
            16, 0, 0);
    __syncthreads();

    // ---- K-loop: 5 taps x 2 ci-halves; 4 af (1KB coalesced, L2-resident) +
    // 2 bf (conflict-free b128) -> 8 mfma_i32_16x16x64_i8.
    // SWAPPED operands (A=X row=l, B=W col=co): D col=co, row=l.
    i32x4 acc[4][2] = {};
    #pragma unroll
    for (int k = 0; k < KW; ++k) {
        #pragma unroll
        for (int s = 0; s < 2; ++s) {
            i32x4 af[4];
            #pragma unroll
            for (int ct = 0; ct < 4; ++ct)
                af[ct] = *(const i32x4*)(
                    wtf + (size_t)((k << 5) + (s << 4) + (cog >> 4) + ct) * 1024 + lane * 16);
            i32x4 bf[2];
            int chunk = (s << 2) + lh;
            #pragma unroll
            for (int lt = 0; lt < 2; ++lt) {
                int row = wl + (lt << 4) + lr + k + 2;
                bf[lt] = *(const i32x4*)(smem + (row << 7) + ((chunk ^ (row & 7)) << 4));
            }
            #pragma unroll
            for (int ct = 0; ct < 4; ++ct)
                #pragma unroll
                for (int lt = 0; lt < 2; ++lt)
                    acc[ct][lt] = __builtin_amdgcn_mfma_i32_16x16x64_i8(
                        bf[lt], af[ct], acc[ct][lt], 0, 0, 0);
        }
    }

    // ---- requant epilogue: col=co=cog+ct*16+lr (per-lane sc/off), row=l.
    // acc[ct][lt] = 4 consecutive l at fixed co -> one dwordx4 store each.
    // (float)int32 is exact (|sum| <= 10.3M < 2^24).
    size_t outb = (size_t)b * COUT * LEN;
    #pragma unroll
    for (int ct = 0; ct < 4; ++ct) {
        int co = cog + (ct << 4) + lr;
        float scv = tbl[co];
        float off = tbl[256 + co];
        int* orow = out + outb + (size_t)co * LEN + l0 + wl + (lh << 2);
        #pragma unroll
        for (int lt = 0; lt < 2; ++lt) {
            i32x4 pk;
            #pragma unroll
            for (int r = 0; r < 4; ++r) {
                float o = rintf(fmaf((float)acc[ct][lt][r], scv, off));
                o = fminf(fmaxf(o, -128.0f), 127.0f);
                pk[r] = (int)o;
            }
            *(i32x4*)(orow + (lt << 4)) = pk;
        }
    }
}

extern "C" void kernel_launch(void* const* d_in, const int* in_sizes, int n_in,
                              void* d_out, int out_size, void* d_ws, size_t ws_size,
                              hipStream_t stream)
{
    const float* x    = (const float*)d_in[0];
    const int*   w    = (const int*)d_in[1];
    const int*   bias = (const int*)d_in[2];
    const float* wsc  = (const float*)d_in[3];
    int* out = (int*)d_out;

    s8*    xqs = (s8*)d_ws;                    // 16,809,984 B
    s8*    wtf = xqs + XQS_BYTES;              // +163,840 B
    float* tbl = (float*)(wtf + WTF_BYTES);    // +2 KB   (total ~17.0 MB)

    prep_kernel<<<dim3(584), dim3(256), 0, stream>>>(x, w, bias, wsc, xqs, wtf, tbl);
    conv_fused<<<dim3(2048), dim3(512), 0, stream>>>(xqs, wtf, tbl, out);
}

// Round 14
// 56.037 us; speedup vs baseline: 1.2172x; 1.2172x over previous
//
#include <hip/hip_runtime.h>

// QuantizedConv1d on MI355X (gfx950) — round 14: fused, full-co blocks
// B=32, CIN=128, L=4096, COUT=256, K=5, replication pad 2.
//   wprep_kernel: W int32 -> fragment-linear i8 wtf[160][64][16B] + tbl (tiny)
//   conv_fused:   block = 256co x 128l, 512 thr, 8 waves = 4co x 2l,
//                 wave = 64co x 64l (acc[4][4]). In-kernel quantize+transpose
//                 staging (each x element ONCE), swizzled LDS (0 conflicts,
//                 verified r10-12), i8 MFMA swapped operands, dwordx4 epilogue.
// Round-13 post-mortem: 32l wave tile halved MFMA:af ratio -> regression.
// Round-14 = r11's verified 64co x 64l wave + full-co block (halves chip-wide
// quant/staging vs r11) + no separate x-prep dispatch (vs r12).

#define B_    32
#define CIN   128
#define LEN   4096
#define COUT  256
#define KW    5
#define TROWS 136   // staged rows: gl in [l0-4, l0+131]

#define WTF_BYTES (KW * 2 * 16 * 64 * 16)   // 163,840

typedef int          i32x4 __attribute__((ext_vector_type(4)));
typedef signed char  s8;

// round-half-even(x*20) - 3, clip to [-128,127], as int8.
// (x*20f vs x/0.05f: <=1ulp flips ~1e-6/elem, each moves an output <=0.64 —
// inside the 2.56 absmax threshold; validated passing rounds 6/8-13.)
__device__ __forceinline__ s8 quant_i8(float xv) {
    float q = rintf(xv * 20.0f) - 3.0f;
    q = fminf(fmaxf(q, -128.0f), 127.0f);
    return (s8)(int)q;
}

// W -> fragment-linear i8: frag = k*32 + s*16 + co16; lane holds
// W[co16*16 + (lane&15)][ci = s*64 + (lane>>4)*16 + j], j=0..15.
__global__ __launch_bounds__(256) void wprep_kernel(
        const int* __restrict__ w, const int* __restrict__ bias,
        const float* __restrict__ wscale,
        s8* __restrict__ wtf, float* __restrict__ tbl)
{
    int o    = blockIdx.x * 256 + threadIdx.x;   // 0..10239
    int lane = o & 63, frag = o >> 6;            // frag 0..159
    int k    = frag >> 5;
    int s    = (frag >> 4) & 1;
    int co   = ((frag & 15) << 4) + (lane & 15);
    int ci   = (s << 6) + ((lane >> 4) << 4);
    union { s8 c[16]; i32x4 v; } q;
    #pragma unroll
    for (int j = 0; j < 16; ++j)
        q.c[j] = (s8)w[co * (CIN * KW) + (ci + j) * KW + k];   // |v|<=127
    *(i32x4*)(wtf + (size_t)frag * 1024 + lane * 16) = q.v;

    if (blockIdx.x == 0) {                        // requant table: sc, off
        int c = threadIdx.x;                      // 0..255
        float sc = __fdiv_rn(__fmul_rn(0.05f, wscale[c]), 0.1f);
        tbl[c]       = sc;
        tbl[256 + c] = fmaf((float)bias[c], sc, -128.0f);
    }
}

// Block: 256 co x 128 l, 512 threads, 8 waves = 4 co-waves x 2 l-waves.
// Wave = 64co x 64l, acc[4][4]. LDS: [136 rows][128 ci] i8, 17,408 B,
// swizzle: 16B-chunk ^= (row & 7) — measured 0 conflicts (r10-12).
// launch_bounds(512,4): 128-reg cap, 2 blocks/CU = 16 waves.
// Grid 1024 = B(32) x ltile(32), XCD-chunked bijective remap (1024 = 8x128).
__global__ __launch_bounds__(512, 4) void conv_fused(
        const float* __restrict__ x, const s8* __restrict__ wtf,
        const float* __restrict__ tbl, int* __restrict__ out)
{
    __shared__ __align__(16) s8 smem[TROWS * CIN];   // 17,408 B

    int orig  = (blockIdx.x & 7) * 128 + (blockIdx.x >> 3);
    int ltile = orig & 31;
    int b     = orig >> 5;
    int l0    = ltile << 7;
    int tid   = threadIdx.x;
    int wid   = tid >> 6, lane = tid & 63;
    int lr    = lane & 15, lh = lane >> 4;
    int cog   = (wid & 3) << 6;          // wave co base: 4 x 64
    int wl    = (wid >> 2) << 6;         // wave local-l base {0, 64}

    const float* xb = x + (size_t)b * CIN * LEN;

    // ---- stage: quantize + transpose rows [l0-4, l0+131] (clamped) ----
    // Task p = (rowblock p>>3, chunk c=p&7); lane = row offset (stride-1):
    // each of 16 loads is 64 consecutive dwords (coalesced); one b128 LDS
    // write per 16-ci chunk at swizzled slot (conflict-free both sides).
    for (int p = wid; p < 24; p += 8) {
        int row = ((p >> 3) << 6) + lane;
        int c   = p & 7;
        if (row < TROWS) {
            int gl = l0 - 4 + row;
            gl = min(max(gl, 0), LEN - 1);
            const float* src = xb + (size_t)(c << 4) * LEN + gl;
            union { s8 cc[16]; i32x4 v; } q;
            #pragma unroll
            for (int j = 0; j < 16; ++j)
                q.cc[j] = quant_i8(src[(size_t)j * LEN]);
            *(i32x4*)(smem + (row << 7) + ((c ^ (row & 7)) << 4)) = q.v;
        }
    }
    __syncthreads();

    // ---- K-loop: 5 taps x 2 ci-halves; 4 af (1KB coalesced, L2-resident) +
    // 4 bf (conflict-free b128) -> 16 mfma_i32_16x16x64_i8.
    // SWAPPED operands (A=X row=l, B=W col=co): D col=co, row=l.
    i32x4 acc[4][4] = {};
    #pragma unroll
    for (int k = 0; k < KW; ++k) {
        #pragma unroll
        for (int s = 0; s < 2; ++s) {
            i32x4 af[4];
            #pragma unroll
            for (int ct = 0; ct < 4; ++ct)
                af[ct] = *(const i32x4*)(
                    wtf + (size_t)((k << 5) + (s << 4) + (cog >> 4) + ct) * 1024 + lane * 16);
            i32x4 bf[4];
            int chunk = (s << 2) + lh;
            #pragma unroll
            for (int lt = 0; lt < 4; ++lt) {
                int row = wl + (lt << 4) + lr + k + 2;
                bf[lt] = *(const i32x4*)(smem + (row << 7) + ((chunk ^ (row & 7)) << 4));
            }
            #pragma unroll
            for (int ct = 0; ct < 4; ++ct)
                #pragma unroll
                for (int lt = 0; lt < 4; ++lt)
                    acc[ct][lt] = __builtin_amdgcn_mfma_i32_16x16x64_i8(
                        bf[lt], af[ct], acc[ct][lt], 0, 0, 0);
        }
    }

    // ---- requant epilogue: col=co=cog+ct*16+lr (per-lane sc/off), row=l.
    // acc[ct][lt] = 4 consecutive l at fixed co -> one dwordx4 store each.
    // (float)int32 is exact (|sum| <= 10.3M < 2^24).
    size_t outb = (size_t)b * COUT * LEN;
    #pragma unroll
    for (int ct = 0; ct < 4; ++ct) {
        int co = cog + (ct << 4) + lr;
        float scv = tbl[co];
        float off = tbl[256 + co];
        int* orow = out + outb + (size_t)co * LEN + l0 + wl + (lh << 2);
        #pragma unroll
        for (int lt = 0; lt < 4; ++lt) {
            i32x4 pk;
            #pragma unroll
            for (int r = 0; r < 4; ++r) {
                float o = rintf(fmaf((float)acc[ct][lt][r], scv, off));
                o = fminf(fmaxf(o, -128.0f), 127.0f);
                pk[r] = (int)o;
            }
            *(i32x4*)(orow + (lt << 4)) = pk;
        }
    }
}

extern "C" void kernel_launch(void* const* d_in, const int* in_sizes, int n_in,
                              void* d_out, int out_size, void* d_ws, size_t ws_size,
                              hipStream_t stream)
{
    const float* x    = (const float*)d_in[0];
    const int*   w    = (const int*)d_in[1];
    const int*   bias = (const int*)d_in[2];
    const float* wsc  = (const float*)d_in[3];
    int* out = (int*)d_out;

    s8*    wtf = (s8*)d_ws;                         // 163,840 B
    float* tbl = (float*)((char*)d_ws + WTF_BYTES); // +2 KB

    wprep_kernel<<<dim3(40), dim3(256), 0, stream>>>(w, bias, wsc, wtf, tbl);
    conv_fused<<<dim3(1024), dim3(512), 0, stream>>>(x, wtf, tbl, out);
}

// Round 15
// 54.964 us; speedup vs baseline: 1.2410x; 1.0195x over previous
//
#include <hip/hip_runtime.h>

// QuantizedConv1d on MI355X (gfx950) — round 15: flattened staging latency
// B=32, CIN=128, L=4096, COUT=256, K=5, replication pad 2.
//   wprep_kernel: W int32 -> fragment-linear i8 wtf[160][64][16B] + tbl (tiny)
//   conv_fused:   block = 256co x 128l, 512 thr, 8 waves = 4co x 2l,
//                 wave = 64co x 64l (acc[4][4]). Staging: ALL 32 main loads
//                 issued upfront (static reg arrays), then quant+write, then
//                 8-lane tail — 1 HBM latency instead of 3 serial rounds.
//                 i8 MFMA swapped operands, dwordx4 epilogue (r14-verified).
// Round-14 post-mortem: 56.0us best; ~21us over the 31us HBM floor is
// latency chains; staging was 3 serial load->wait->quant->write rounds.

#define B_    32
#define CIN   128
#define LEN   4096
#define COUT  256
#define KW    5
#define TROWS 136   // staged rows: gl in [l0-4, l0+131]

#define WTF_BYTES (KW * 2 * 16 * 64 * 16)   // 163,840

typedef int          i32x4 __attribute__((ext_vector_type(4)));
typedef signed char  s8;

// round-half-even(x*20 - 3), clip to [-128,127], as int8.
// fmaf fold: differs from round(x/0.05)+(-3) only on ~1e-6 tie flips, each
// moving an output by <=1 step — absmax has been 1.0 (threshold 2.56) since r6.
__device__ __forceinline__ s8 quant_i8(float xv) {
    float q = rintf(fmaf(xv, 20.0f, -3.0f));
    q = fminf(fmaxf(q, -128.0f), 127.0f);
    return (s8)(int)q;
}

// W -> fragment-linear i8: frag = k*32 + s*16 + co16; lane holds
// W[co16*16 + (lane&15)][ci = s*64 + (lane>>4)*16 + j], j=0..15.
__global__ __launch_bounds__(256) void wprep_kernel(
        const int* __restrict__ w, const int* __restrict__ bias,
        const float* __restrict__ wscale,
        s8* __restrict__ wtf, float* __restrict__ tbl)
{
    int o    = blockIdx.x * 256 + threadIdx.x;   // 0..10239
    int lane = o & 63, frag = o >> 6;            // frag 0..159
    int k    = frag >> 5;
    int s    = (frag >> 4) & 1;
    int co   = ((frag & 15) << 4) + (lane & 15);
    int ci   = (s << 6) + ((lane >> 4) << 4);
    union { s8 c[16]; i32x4 v; } q;
    #pragma unroll
    for (int j = 0; j < 16; ++j)
        q.c[j] = (s8)w[co * (CIN * KW) + (ci + j) * KW + k];   // |v|<=127
    *(i32x4*)(wtf + (size_t)frag * 1024 + lane * 16) = q.v;

    if (blockIdx.x == 0) {                        // requant table: sc, off
        int c = threadIdx.x;                      // 0..255
        float sc = __fdiv_rn(__fmul_rn(0.05f, wscale[c]), 0.1f);
        tbl[c]       = sc;
        tbl[256 + c] = fmaf((float)bias[c], sc, -128.0f);
    }
}

// Block: 256 co x 128 l, 512 threads, 8 waves = 4 co-waves x 2 l-waves.
// Wave = 64co x 64l, acc[4][4]. LDS: [136 rows][128 ci] i8, 17,408 B,
// swizzle: 16B-chunk ^= (row & 7) — measured 0 conflicts (r10-12).
// launch_bounds(512,4): 128-reg cap, 2 blocks/CU = 16 waves.
// Grid 1024 = B(32) x ltile(32), XCD-chunked bijective remap (1024 = 8x128).
__global__ __launch_bounds__(512, 4) void conv_fused(
        const float* __restrict__ x, const s8* __restrict__ wtf,
        const float* __restrict__ tbl, int* __restrict__ out)
{
    __shared__ __align__(16) s8 smem[TROWS * CIN];   // 17,408 B

    int orig  = (blockIdx.x & 7) * 128 + (blockIdx.x >> 3);
    int ltile = orig & 31;
    int b     = orig >> 5;
    int l0    = ltile << 7;
    int tid   = threadIdx.x;
    int wid   = tid >> 6, lane = tid & 63;
    int lr    = lane & 15, lh = lane >> 4;
    int cog   = (wid & 3) << 6;          // wave co base: 4 x 64
    int wl    = (wid >> 2) << 6;         // wave local-l base {0, 64}

    const float* xb = x + (size_t)b * CIN * LEN;

    // ---- stage: quantize + transpose rows [l0-4, l0+131] (clamped) ----
    // Wave wid owns ci-chunk c = wid (16 ci). Rows: lane, 64+lane, 128+lane(<8).
    // All 32 main loads issued upfront -> one HBM-latency wait, not three.
    {
        const float* src = xb + (size_t)(wid << 4) * LEN;
        int gl0 = min(max(l0 - 4 + lane, 0), LEN - 1);
        int gl1 = min(max(l0 + 60 + lane, 0), LEN - 1);
        float v0[16], v1[16];
        #pragma unroll
        for (int j = 0; j < 16; ++j) {
            v0[j] = src[(size_t)j * LEN + gl0];
            v1[j] = src[(size_t)j * LEN + gl1];
        }
        union { s8 cc[16]; i32x4 v; } q0, q1;
        #pragma unroll
        for (int j = 0; j < 16; ++j) q0.cc[j] = quant_i8(v0[j]);
        #pragma unroll
        for (int j = 0; j < 16; ++j) q1.cc[j] = quant_i8(v1[j]);
        int row0 = lane, row1 = 64 + lane;
        *(i32x4*)(smem + (row0 << 7) + ((wid ^ (row0 & 7)) << 4)) = q0.v;
        *(i32x4*)(smem + (row1 << 7) + ((wid ^ (row1 & 7)) << 4)) = q1.v;
        if (lane < 8) {                    // tail rows 128..135
            int row2 = 128 + lane;
            int gl2 = min(max(l0 + 124 + lane, 0), LEN - 1);
            union { s8 cc[16]; i32x4 v; } q2;
            #pragma unroll
            for (int j = 0; j < 16; ++j)
                q2.cc[j] = quant_i8(src[(size_t)j * LEN + gl2]);
            *(i32x4*)(smem + (row2 << 7) + ((wid ^ (row2 & 7)) << 4)) = q2.v;
        }
    }
    __syncthreads();

    // ---- K-loop: 5 taps x 2 ci-halves; 4 af (1KB coalesced, L2-resident) +
    // 4 bf (conflict-free b128) -> 16 mfma_i32_16x16x64_i8.
    // SWAPPED operands (A=X row=l, B=W col=co): D col=co, row=l.
    i32x4 acc[4][4] = {};
    #pragma unroll
    for (int k = 0; k < KW; ++k) {
        #pragma unroll
        for (int s = 0; s < 2; ++s) {
            i32x4 af[4];
            #pragma unroll
            for (int ct = 0; ct < 4; ++ct)
                af[ct] = *(const i32x4*)(
                    wtf + (size_t)((k << 5) + (s << 4) + (cog >> 4) + ct) * 1024 + lane * 16);
            i32x4 bf[4];
            int chunk = (s << 2) + lh;
            #pragma unroll
            for (int lt = 0; lt < 4; ++lt) {
                int row = wl + (lt << 4) + lr + k + 2;
                bf[lt] = *(const i32x4*)(smem + (row << 7) + ((chunk ^ (row & 7)) << 4));
            }
            #pragma unroll
            for (int ct = 0; ct < 4; ++ct)
                #pragma unroll
                for (int lt = 0; lt < 4; ++lt)
                    acc[ct][lt] = __builtin_amdgcn_mfma_i32_16x16x64_i8(
                        bf[lt], af[ct], acc[ct][lt], 0, 0, 0);
        }
    }

    // ---- requant epilogue: col=co=cog+ct*16+lr (per-lane sc/off), row=l.
    // acc[ct][lt] = 4 consecutive l at fixed co -> one dwordx4 store each.
    // (float)int32 is exact (|sum| <= 10.3M < 2^24).
    size_t outb = (size_t)b * COUT * LEN;
    #pragma unroll
    for (int ct = 0; ct < 4; ++ct) {
        int co = cog + (ct << 4) + lr;
        float scv = tbl[co];
        float off = tbl[256 + co];
        int* orow = out + outb + (size_t)co * LEN + l0 + wl + (lh << 2);
        #pragma unroll
        for (int lt = 0; lt < 4; ++lt) {
            i32x4 pk;
            #pragma unroll
            for (int r = 0; r < 4; ++r) {
                float o = rintf(fmaf((float)acc[ct][lt][r], scv, off));
                o = fminf(fmaxf(o, -128.0f), 127.0f);
                pk[r] = (int)o;
            }
            *(i32x4*)(orow + (lt << 4)) = pk;
        }
    }
}

extern "C" void kernel_launch(void* const* d_in, const int* in_sizes, int n_in,
                              void* d_out, int out_size, void* d_ws, size_t ws_size,
                              hipStream_t stream)
{
    const float* x    = (const float*)d_in[0];
    const int*   w    = (const int*)d_in[1];
    const int*   bias = (const int*)d_in[2];
    const float* wsc  = (const float*)d_in[3];
    int* out = (int*)d_out;

    s8*    wtf = (s8*)d_ws;                         // 163,840 B
    float* tbl = (float*)((char*)d_ws + WTF_BYTES); // +2 KB

    wprep_kernel<<<dim3(40), dim3(256), 0, stream>>>(w, bias, wsc, wtf, tbl);
    conv_fused<<<dim3(1024), dim3(512), 0, stream>>>(x, wtf, tbl, out);
}